// Round 2
// baseline (185.191 us; speedup 1.0000x reference)
//
#include <hip/hip_runtime.h>
#include <hip/hip_bf16.h>
#include <math.h>

// ComplexEMA: y[b,d,l] = sum_n Re(gp[d,n] * s[n,l]) + omega[d]*x[b,d,l]
//   s[n,l] = q[d,n]*s[n,l-1] + x[b,d,l],  q = radius*exp(i*phi), |q|<1
// Chunked parallel scan, one wave per (b,d) row, lane = 32-element chunk.
// LDS layout: chunk-major with XOR swizzle so ALL LDS traffic is
// conflict-free ds_read_b128/ds_write_b128:
//   word(row, c, j) = row*2048 + c*32 + 4*((j>>2) ^ (c&7)) + (j&3)

#define B 8
#define D 1024
#define L 2048
#define NM 16
#define CHUNK 32

__global__ void coeff_kernel(const float* __restrict__ alpha,
                             const float* __restrict__ delta,
                             const float* __restrict__ theta,
                             const float* __restrict__ gamma_r,
                             const float* __restrict__ gamma_i,
                             float4* __restrict__ coef) {
    int idx = blockIdx.x * blockDim.x + threadIdx.x;   // (d,n) flat
    if (idx >= D * NM) return;
    int d = idx >> 4;
    int n = idx & 15;
    float a  = 1.0f / (1.0f + __expf(-alpha[idx]));
    float dd = 1.0f / (1.0f + __expf(-delta[idx]));
    float th = (1.0f / (1.0f + __expf(-theta[d]))) * (2.0f * 3.14159265358979323846f / (float)NM);
    float phi = (float)(n + 1) * th;
    float radius = fminf(1.0f - a * dd, 1.0f);
    float sn, cs;
    __sincosf(phi, &sn, &cs);
    float scale = 0.25f * a;                  // sqrt(1/N)=0.25 times p=a
    // store q, gp_r, -gp_i (pre-negated so pass2 is two FMAs per mode)
    coef[idx] = make_float4(radius * cs, radius * sn,
                            gamma_r[idx] * scale, -gamma_i[idx] * scale);
}

__global__ __launch_bounds__(256, 4) void ema_kernel(const float* __restrict__ x,
                                                     const float4* __restrict__ coef,
                                                     const float* __restrict__ omega,
                                                     float* __restrict__ out) {
    __shared__ float lds[4 * L];              // 32 KiB, no pad needed (swizzle)
    const int tid  = threadIdx.x;
    const int wave = tid >> 6;
    const int lane = tid & 63;
    const size_t blockBase = (size_t)blockIdx.x * (4 * L);   // 4 rows per block

    // ---- stage x -> LDS (coalesced float4 reads, swizzled b128 writes)
    {
        const float4* xv = (const float4*)(x + blockBase);
        #pragma unroll
        for (int k = 0; k < 8; ++k) {
            int g4  = tid + 256 * k;          // float4 index in block (0..2047)
            float4 v = xv[g4];
            int g   = g4 << 2;
            int row = g >> 11;
            int l   = g & (L - 1);
            int c   = l >> 5;
            int jb  = (l >> 2) & 7;
            int w   = row * L + c * 32 + (((jb ^ (c & 7))) << 2);
            *(float4*)&lds[w] = v;
        }
    }
    __syncthreads();

    const int rowIdx = blockIdx.x * 4 + wave;   // global (b,d) row
    const int d = rowIdx & (D - 1);
    const float4* cf = coef + d * NM;

    float* xrow = lds + wave * L;
    const int cbase = lane * 32;
    const int cx7   = lane & 7;

    // ---- load q only (gamma loaded after the scan to cut VGPR peak)
    float qr[NM], qi[NM];
    #pragma unroll
    for (int n = 0; n < NM; ++n) {
        float4 c = cf[n];
        qr[n] = c.x; qi[n] = c.y;
    }

    // ---- pass 1: chunk-local end states (zero init)
    float sr[NM], si[NM];
    #pragma unroll
    for (int n = 0; n < NM; ++n) { sr[n] = 0.0f; si[n] = 0.0f; }
    #pragma unroll
    for (int jb = 0; jb < 8; ++jb) {
        float4 xq = *(const float4*)&xrow[cbase + ((jb ^ cx7) << 2)];
        #pragma unroll
        for (int jj = 0; jj < 4; ++jj) {
            float xv = (&xq.x)[jj];
            #pragma unroll
            for (int n = 0; n < NM; ++n) {
                float tr = fmaf(qr[n], sr[n], fmaf(-qi[n], si[n], xv));
                float ti = fmaf(qr[n], si[n], qi[n] * sr[n]);
                sr[n] = tr; si[n] = ti;
            }
        }
    }

    // ---- Kogge-Stone inclusive scan across 64 lanes, weight w = q^CHUNK
    float wr[NM], wi[NM];
    #pragma unroll
    for (int n = 0; n < NM; ++n) { wr[n] = qr[n]; wi[n] = qi[n]; }
    #pragma unroll
    for (int t = 0; t < 5; ++t) {            // q -> q^32
        #pragma unroll
        for (int n = 0; n < NM; ++n) {
            float t2 = fmaf(wr[n], wr[n], -(wi[n] * wi[n]));
            wi[n] = 2.0f * wr[n] * wi[n];
            wr[n] = t2;
        }
    }
    #pragma unroll
    for (int k = 1; k <= 32; k <<= 1) {
        #pragma unroll
        for (int n = 0; n < NM; ++n) {
            float or_ = __shfl_up(sr[n], (unsigned)k, 64);
            float oi_ = __shfl_up(si[n], (unsigned)k, 64);
            if (lane >= k) {
                sr[n] = fmaf(wr[n], or_, fmaf(-wi[n], oi_, sr[n]));
                si[n] = fmaf(wr[n], oi_, fmaf(wi[n], or_, si[n]));
            }
        }
        if (k != 32) {
            #pragma unroll
            for (int n = 0; n < NM; ++n) {   // w -> w^2 for next distance
                float t2 = fmaf(wr[n], wr[n], -(wi[n] * wi[n]));
                wi[n] = 2.0f * wr[n] * wi[n];
                wr[n] = t2;
            }
        }
    }
    // exclusive: incoming carry for this chunk
    #pragma unroll
    for (int n = 0; n < NM; ++n) {
        float cr = __shfl_up(sr[n], 1u, 64);
        float ci = __shfl_up(si[n], 1u, 64);
        sr[n] = (lane == 0) ? 0.0f : cr;
        si[n] = (lane == 0) ? 0.0f : ci;
    }

    // ---- load gamma now (post-scan; reuses the wr/wi register space)
    float gr[NM], gin[NM];
    #pragma unroll
    for (int n = 0; n < NM; ++n) {
        float4 c = cf[n];
        gr[n] = c.z; gin[n] = c.w;           // c.w pre-negated
    }
    const float om = omega[d];

    // ---- pass 2: rescan with carry, emit y (staggered read-ahead so the
    //      b128 write of y[jb] never blocks the read of x[jb+1])
    float4 xq = *(const float4*)&xrow[cbase + ((0 ^ cx7) << 2)];
    #pragma unroll
    for (int jb = 0; jb < 8; ++jb) {
        float4 xn;
        if (jb < 7) xn = *(const float4*)&xrow[cbase + (((jb + 1) ^ cx7) << 2)];
        float4 aq;
        #pragma unroll
        for (int jj = 0; jj < 4; ++jj) {
            float xv = (&xq.x)[jj];
            float acc = om * xv;
            #pragma unroll
            for (int n = 0; n < NM; ++n) {
                float tr = fmaf(qr[n], sr[n], fmaf(-qi[n], si[n], xv));
                float ti = fmaf(qr[n], si[n], qi[n] * sr[n]);
                sr[n] = tr; si[n] = ti;
                acc = fmaf(gr[n], tr, acc);
                acc = fmaf(gin[n], ti, acc);
            }
            (&aq.x)[jj] = acc;
        }
        *(float4*)&xrow[cbase + ((jb ^ cx7) << 2)] = aq;
        xq = xn;
    }
    __syncthreads();

    // ---- LDS -> global (swizzled b128 reads, coalesced float4 writes)
    {
        float4* dst = (float4*)(out + blockBase);
        #pragma unroll
        for (int k = 0; k < 8; ++k) {
            int g4  = tid + 256 * k;
            int g   = g4 << 2;
            int row = g >> 11;
            int l   = g & (L - 1);
            int c   = l >> 5;
            int jb  = (l >> 2) & 7;
            int w   = row * L + c * 32 + (((jb ^ (c & 7))) << 2);
            dst[g4] = *(const float4*)&lds[w];
        }
    }
}

extern "C" void kernel_launch(void* const* d_in, const int* in_sizes, int n_in,
                              void* d_out, int out_size, void* d_ws, size_t ws_size,
                              hipStream_t stream) {
    const float* x       = (const float*)d_in[0];
    const float* alpha   = (const float*)d_in[1];
    const float* delta   = (const float*)d_in[2];
    const float* theta   = (const float*)d_in[3];
    const float* gamma_r = (const float*)d_in[4];
    const float* gamma_i = (const float*)d_in[5];
    const float* omega   = (const float*)d_in[6];
    float* out = (float*)d_out;
    float4* coef = (float4*)d_ws;            // D*NM float4 = 256 KiB

    coeff_kernel<<<(D * NM + 255) / 256, 256, 0, stream>>>(alpha, delta, theta,
                                                           gamma_r, gamma_i, coef);
    ema_kernel<<<(B * D) / 4, 256, 0, stream>>>(x, coef, omega, out);
}

// Round 3
// 88.342 us; speedup vs baseline: 2.0963x; 2.0963x over previous
//
#include <hip/hip_runtime.h>
#include <hip/hip_bf16.h>
#include <math.h>

// ComplexEMA: y[b,d,l] = sum_n Re(gp[d,n] * s[n,l]) + omega[d]*x[b,d,l]
//   s[n,l] = q[d,n]*s[n,l-1] + x[b,d,l],  q = radius*exp(i*phi), |q|<1
// Chunked parallel scan, one wave per (b,d) row, lane = 32-element chunk.
// LDS layout: chunk-major with XOR swizzle so ALL LDS traffic is
// conflict-free ds_read_b128/ds_write_b128:
//   word(row, c, j) = row*2048 + c*32 + 4*((j>>2) ^ (c&7)) + (j&3)
// NOTE (R2 post-mortem): do NOT set a min-waves arg in __launch_bounds__ —
// capping VGPR at 64 spills the ~96-reg live set to scratch (WRITE_SIZE 3.7x).

#define B 8
#define D 1024
#define L 2048
#define NM 16
#define CHUNK 32

__global__ void coeff_kernel(const float* __restrict__ alpha,
                             const float* __restrict__ delta,
                             const float* __restrict__ theta,
                             const float* __restrict__ gamma_r,
                             const float* __restrict__ gamma_i,
                             float4* __restrict__ coef) {
    int idx = blockIdx.x * blockDim.x + threadIdx.x;   // (d,n) flat
    if (idx >= D * NM) return;
    int d = idx >> 4;
    int n = idx & 15;
    float a  = 1.0f / (1.0f + __expf(-alpha[idx]));
    float dd = 1.0f / (1.0f + __expf(-delta[idx]));
    float th = (1.0f / (1.0f + __expf(-theta[d]))) * (2.0f * 3.14159265358979323846f / (float)NM);
    float phi = (float)(n + 1) * th;
    float radius = fminf(1.0f - a * dd, 1.0f);
    float sn, cs;
    __sincosf(phi, &sn, &cs);
    float scale = 0.25f * a;                  // sqrt(1/N)=0.25 times p=a
    // store q, gp_r, -gp_i (pre-negated so pass2 is two FMAs per mode)
    coef[idx] = make_float4(radius * cs, radius * sn,
                            gamma_r[idx] * scale, -gamma_i[idx] * scale);
}

__global__ __launch_bounds__(256) void ema_kernel(const float* __restrict__ x,
                                                  const float4* __restrict__ coef,
                                                  const float* __restrict__ omega,
                                                  float* __restrict__ out) {
    __shared__ float lds[4 * L];              // 32 KiB, no pad needed (swizzle)
    const int tid  = threadIdx.x;
    const int wave = tid >> 6;
    const int lane = tid & 63;
    const size_t blockBase = (size_t)blockIdx.x * (4 * L);   // 4 rows per block

    // ---- stage x -> LDS (coalesced float4 reads, swizzled b128 writes)
    {
        const float4* xv = (const float4*)(x + blockBase);
        #pragma unroll
        for (int k = 0; k < 8; ++k) {
            int g4  = tid + 256 * k;          // float4 index in block (0..2047)
            float4 v = xv[g4];
            int g   = g4 << 2;
            int row = g >> 11;
            int l   = g & (L - 1);
            int c   = l >> 5;
            int jb  = (l >> 2) & 7;
            int w   = row * L + c * 32 + (((jb ^ (c & 7))) << 2);
            *(float4*)&lds[w] = v;
        }
    }
    __syncthreads();

    const int rowIdx = blockIdx.x * 4 + wave;   // global (b,d) row
    const int d = rowIdx & (D - 1);
    const float4* cf = coef + d * NM;

    float* xrow = lds + wave * L;
    const int cbase = lane * 32;
    const int cx7   = lane & 7;

    // ---- load q only (gamma loaded after the scan to cut VGPR peak)
    float qr[NM], qi[NM];
    #pragma unroll
    for (int n = 0; n < NM; ++n) {
        float4 c = cf[n];
        qr[n] = c.x; qi[n] = c.y;
    }

    // ---- pass 1: chunk-local end states (zero init)
    float sr[NM], si[NM];
    #pragma unroll
    for (int n = 0; n < NM; ++n) { sr[n] = 0.0f; si[n] = 0.0f; }
    #pragma unroll
    for (int jb = 0; jb < 8; ++jb) {
        float4 xq = *(const float4*)&xrow[cbase + ((jb ^ cx7) << 2)];
        #pragma unroll
        for (int jj = 0; jj < 4; ++jj) {
            float xv = (&xq.x)[jj];
            #pragma unroll
            for (int n = 0; n < NM; ++n) {
                float tr = fmaf(qr[n], sr[n], fmaf(-qi[n], si[n], xv));
                float ti = fmaf(qr[n], si[n], qi[n] * sr[n]);
                sr[n] = tr; si[n] = ti;
            }
        }
    }

    // ---- Kogge-Stone inclusive scan across 64 lanes, weight w = q^CHUNK
    float wr[NM], wi[NM];
    #pragma unroll
    for (int n = 0; n < NM; ++n) { wr[n] = qr[n]; wi[n] = qi[n]; }
    #pragma unroll
    for (int t = 0; t < 5; ++t) {            // q -> q^32
        #pragma unroll
        for (int n = 0; n < NM; ++n) {
            float t2 = fmaf(wr[n], wr[n], -(wi[n] * wi[n]));
            wi[n] = 2.0f * wr[n] * wi[n];
            wr[n] = t2;
        }
    }
    #pragma unroll
    for (int k = 1; k <= 32; k <<= 1) {
        #pragma unroll
        for (int n = 0; n < NM; ++n) {
            float or_ = __shfl_up(sr[n], (unsigned)k, 64);
            float oi_ = __shfl_up(si[n], (unsigned)k, 64);
            if (lane >= k) {
                sr[n] = fmaf(wr[n], or_, fmaf(-wi[n], oi_, sr[n]));
                si[n] = fmaf(wr[n], oi_, fmaf(wi[n], or_, si[n]));
            }
        }
        if (k != 32) {
            #pragma unroll
            for (int n = 0; n < NM; ++n) {   // w -> w^2 for next distance
                float t2 = fmaf(wr[n], wr[n], -(wi[n] * wi[n]));
                wi[n] = 2.0f * wr[n] * wi[n];
                wr[n] = t2;
            }
        }
    }
    // exclusive: incoming carry for this chunk
    #pragma unroll
    for (int n = 0; n < NM; ++n) {
        float cr = __shfl_up(sr[n], 1u, 64);
        float ci = __shfl_up(si[n], 1u, 64);
        sr[n] = (lane == 0) ? 0.0f : cr;
        si[n] = (lane == 0) ? 0.0f : ci;
    }

    // ---- load gamma now (post-scan; reuses the wr/wi register space)
    float gr[NM], gin[NM];
    #pragma unroll
    for (int n = 0; n < NM; ++n) {
        float4 c = cf[n];
        gr[n] = c.z; gin[n] = c.w;           // c.w pre-negated
    }
    const float om = omega[d];

    // ---- pass 2: rescan with carry, emit y (staggered read-ahead so the
    //      b128 write of y[jb] never blocks the read of x[jb+1])
    float4 xq = *(const float4*)&xrow[cbase + ((0 ^ cx7) << 2)];
    #pragma unroll
    for (int jb = 0; jb < 8; ++jb) {
        float4 xn;
        if (jb < 7) xn = *(const float4*)&xrow[cbase + (((jb + 1) ^ cx7) << 2)];
        float4 aq;
        #pragma unroll
        for (int jj = 0; jj < 4; ++jj) {
            float xv = (&xq.x)[jj];
            float acc = om * xv;
            #pragma unroll
            for (int n = 0; n < NM; ++n) {
                float tr = fmaf(qr[n], sr[n], fmaf(-qi[n], si[n], xv));
                float ti = fmaf(qr[n], si[n], qi[n] * sr[n]);
                sr[n] = tr; si[n] = ti;
                acc = fmaf(gr[n], tr, acc);
                acc = fmaf(gin[n], ti, acc);
            }
            (&aq.x)[jj] = acc;
        }
        *(float4*)&xrow[cbase + ((jb ^ cx7) << 2)] = aq;
        xq = xn;
    }
    __syncthreads();

    // ---- LDS -> global (swizzled b128 reads, coalesced float4 writes)
    {
        float4* dst = (float4*)(out + blockBase);
        #pragma unroll
        for (int k = 0; k < 8; ++k) {
            int g4  = tid + 256 * k;
            int g   = g4 << 2;
            int row = g >> 11;
            int l   = g & (L - 1);
            int c   = l >> 5;
            int jb  = (l >> 2) & 7;
            int w   = row * L + c * 32 + (((jb ^ (c & 7))) << 2);
            dst[g4] = *(const float4*)&lds[w];
        }
    }
}

extern "C" void kernel_launch(void* const* d_in, const int* in_sizes, int n_in,
                              void* d_out, int out_size, void* d_ws, size_t ws_size,
                              hipStream_t stream) {
    const float* x       = (const float*)d_in[0];
    const float* alpha   = (const float*)d_in[1];
    const float* delta   = (const float*)d_in[2];
    const float* theta   = (const float*)d_in[3];
    const float* gamma_r = (const float*)d_in[4];
    const float* gamma_i = (const float*)d_in[5];
    const float* omega   = (const float*)d_in[6];
    float* out = (float*)d_out;
    float4* coef = (float4*)d_ws;            // D*NM float4 = 256 KiB

    coeff_kernel<<<(D * NM + 255) / 256, 256, 0, stream>>>(alpha, delta, theta,
                                                           gamma_r, gamma_i, coef);
    ema_kernel<<<(B * D) / 4, 256, 0, stream>>>(x, coef, omega, out);
}

// Round 4
// 81.236 us; speedup vs baseline: 2.2797x; 1.0875x over previous
//
#include <hip/hip_runtime.h>
#include <hip/hip_bf16.h>
#include <math.h>

// ComplexEMA: y[b,d,l] = sum_n Re(gp[d,n] * s[n,l]) + omega[d]*x[b,d,l]
//   s[n,l] = q[d,n]*s[n,l-1] + x[b,d,l],  q = radius*exp(i*phi), |q|<1
// Chunked parallel scan, one wave per (b,d) row, lane = 32-element chunk.
// R4: NO LDS. Each lane streams its chunk directly from global as float4s
// (lane*128B + 16B*jb — dense 8KB span per instruction; pass-2 re-read is
// L2-hit). R3 post-mortem: any float4-aligned chunk-major LDS layout has
// only 8 possible start banks -> ~8-way conflict (SQ_LDS_BANK_CONFLICT
// 524288). R2 post-mortem: no min-waves in __launch_bounds__ (spills).

#define B 8
#define D 1024
#define L 2048
#define NM 16
#define CHUNK 32

__global__ void coeff_kernel(const float* __restrict__ alpha,
                             const float* __restrict__ delta,
                             const float* __restrict__ theta,
                             const float* __restrict__ gamma_r,
                             const float* __restrict__ gamma_i,
                             float4* __restrict__ coef) {
    int idx = blockIdx.x * blockDim.x + threadIdx.x;   // (d,n) flat
    if (idx >= D * NM) return;
    int d = idx >> 4;
    int n = idx & 15;
    float a  = 1.0f / (1.0f + __expf(-alpha[idx]));
    float dd = 1.0f / (1.0f + __expf(-delta[idx]));
    float th = (1.0f / (1.0f + __expf(-theta[d]))) * (2.0f * 3.14159265358979323846f / (float)NM);
    float phi = (float)(n + 1) * th;
    float radius = fminf(1.0f - a * dd, 1.0f);
    float sn, cs;
    __sincosf(phi, &sn, &cs);
    float scale = 0.25f * a;                  // sqrt(1/N)=0.25 times p=a
    // store q, gp_r, -gp_i (pre-negated so pass2 is two FMAs per mode)
    coef[idx] = make_float4(radius * cs, radius * sn,
                            gamma_r[idx] * scale, -gamma_i[idx] * scale);
}

__global__ __launch_bounds__(256) void ema_kernel(const float* __restrict__ x,
                                                  const float4* __restrict__ coef,
                                                  const float* __restrict__ omega,
                                                  float* __restrict__ out) {
    const int tid  = threadIdx.x;
    const int wave = tid >> 6;
    const int lane = tid & 63;
    const int rowIdx = blockIdx.x * 4 + wave;     // global (b,d) row
    const int d = rowIdx & (D - 1);

    const float4* xc = (const float4*)(x + (size_t)rowIdx * L + lane * CHUNK);
    float4*       yc = (float4*)(out + (size_t)rowIdx * L + lane * CHUNK);

    // ---- issue first half of the chunk early (hide latency under coef load)
    float4 xa0 = xc[0], xa1 = xc[1], xa2 = xc[2], xa3 = xc[3];

    const float4* cf = coef + d * NM;
    float qr[NM], qi[NM];
    #pragma unroll
    for (int n = 0; n < NM; ++n) {
        float4 c = cf[n];
        qr[n] = c.x; qi[n] = c.y;
    }
    // q^2 (used by pair-step pass1, then seeds the scan-weight squaring)
    float q2r[NM], q2i[NM];
    #pragma unroll
    for (int n = 0; n < NM; ++n) {
        q2r[n] = fmaf(qr[n], qr[n], -(qi[n] * qi[n]));
        q2i[n] = 2.0f * qr[n] * qi[n];
    }

    // ---- pass 1: chunk-local end state via pair-step  s <- q^2 s + (q x1 + x2)
    float sr[NM], si[NM];
    #pragma unroll
    for (int n = 0; n < NM; ++n) { sr[n] = 0.0f; si[n] = 0.0f; }

    {
        float xs[8];
        *(float4*)&xs[0] = xa0; *(float4*)&xs[4] = xa1;
        float4 xb0 = xc[4], xb1 = xc[5];                 // prefetch 2nd half
        #pragma unroll
        for (int p = 0; p < 4; ++p) {
            float x1 = xs[2 * p], x2 = xs[2 * p + 1];
            #pragma unroll
            for (int n = 0; n < NM; ++n) {
                float tr = fmaf(qr[n], x1, x2);
                float ti = qi[n] * x1;
                float nr = fmaf(q2r[n], sr[n], fmaf(-q2i[n], si[n], tr));
                float ni = fmaf(q2r[n], si[n], fmaf(q2i[n], sr[n], ti));
                sr[n] = nr; si[n] = ni;
            }
        }
        *(float4*)&xs[0] = xa2; *(float4*)&xs[4] = xa3;
        float4 xb2 = xc[6], xb3 = xc[7];
        #pragma unroll
        for (int p = 0; p < 4; ++p) {
            float x1 = xs[2 * p], x2 = xs[2 * p + 1];
            #pragma unroll
            for (int n = 0; n < NM; ++n) {
                float tr = fmaf(qr[n], x1, x2);
                float ti = qi[n] * x1;
                float nr = fmaf(q2r[n], sr[n], fmaf(-q2i[n], si[n], tr));
                float ni = fmaf(q2r[n], si[n], fmaf(q2i[n], sr[n], ti));
                sr[n] = nr; si[n] = ni;
            }
        }
        *(float4*)&xs[0] = xb0; *(float4*)&xs[4] = xb1;
        #pragma unroll
        for (int p = 0; p < 4; ++p) {
            float x1 = xs[2 * p], x2 = xs[2 * p + 1];
            #pragma unroll
            for (int n = 0; n < NM; ++n) {
                float tr = fmaf(qr[n], x1, x2);
                float ti = qi[n] * x1;
                float nr = fmaf(q2r[n], sr[n], fmaf(-q2i[n], si[n], tr));
                float ni = fmaf(q2r[n], si[n], fmaf(q2i[n], sr[n], ti));
                sr[n] = nr; si[n] = ni;
            }
        }
        *(float4*)&xs[0] = xb2; *(float4*)&xs[4] = xb3;
        #pragma unroll
        for (int p = 0; p < 4; ++p) {
            float x1 = xs[2 * p], x2 = xs[2 * p + 1];
            #pragma unroll
            for (int n = 0; n < NM; ++n) {
                float tr = fmaf(qr[n], x1, x2);
                float ti = qi[n] * x1;
                float nr = fmaf(q2r[n], sr[n], fmaf(-q2i[n], si[n], tr));
                float ni = fmaf(q2r[n], si[n], fmaf(q2i[n], sr[n], ti));
                sr[n] = nr; si[n] = ni;
            }
        }
    }

    // ---- Kogge-Stone inclusive scan across 64 lanes, weight w = q^CHUNK
    float wr[NM], wi[NM];
    #pragma unroll
    for (int n = 0; n < NM; ++n) { wr[n] = q2r[n]; wi[n] = q2i[n]; }
    #pragma unroll
    for (int t = 0; t < 4; ++t) {            // q^2 -> q^32
        #pragma unroll
        for (int n = 0; n < NM; ++n) {
            float t2 = fmaf(wr[n], wr[n], -(wi[n] * wi[n]));
            wi[n] = 2.0f * wr[n] * wi[n];
            wr[n] = t2;
        }
    }
    #pragma unroll
    for (int k = 1; k <= 32; k <<= 1) {
        #pragma unroll
        for (int n = 0; n < NM; ++n) {
            float or_ = __shfl_up(sr[n], (unsigned)k, 64);
            float oi_ = __shfl_up(si[n], (unsigned)k, 64);
            if (lane >= k) {
                sr[n] = fmaf(wr[n], or_, fmaf(-wi[n], oi_, sr[n]));
                si[n] = fmaf(wr[n], oi_, fmaf(wi[n], or_, si[n]));
            }
        }
        if (k != 32) {
            #pragma unroll
            for (int n = 0; n < NM; ++n) {   // w -> w^2 for next distance
                float t2 = fmaf(wr[n], wr[n], -(wi[n] * wi[n]));
                wi[n] = 2.0f * wr[n] * wi[n];
                wr[n] = t2;
            }
        }
    }
    // exclusive: incoming carry for this chunk
    #pragma unroll
    for (int n = 0; n < NM; ++n) {
        float cr = __shfl_up(sr[n], 1u, 64);
        float ci = __shfl_up(si[n], 1u, 64);
        sr[n] = (lane == 0) ? 0.0f : cr;
        si[n] = (lane == 0) ? 0.0f : ci;
    }

    // ---- load gamma now (post-scan; w regs dead, frees the peak)
    float gr[NM], gin[NM];
    #pragma unroll
    for (int n = 0; n < NM; ++n) {
        float4 c = cf[n];
        gr[n] = c.z; gin[n] = c.w;           // c.w pre-negated
    }
    const float om = omega[d];

    // ---- pass 2: rescan with carry, emit y (2-deep rolling prefetch)
    float4 xq0 = xc[0], xq1 = xc[1];
    #pragma unroll
    for (int jb = 0; jb < 8; ++jb) {
        float4 xn;
        if (jb < 6) xn = xc[jb + 2];
        float4 aq;
        #pragma unroll
        for (int jj = 0; jj < 4; ++jj) {
            float xv = (&xq0.x)[jj];
            float acc = om * xv;
            #pragma unroll
            for (int n = 0; n < NM; ++n) {
                float tr = fmaf(qr[n], sr[n], fmaf(-qi[n], si[n], xv));
                float ti = fmaf(qr[n], si[n], qi[n] * sr[n]);
                sr[n] = tr; si[n] = ti;
                acc = fmaf(gr[n], tr, acc);
                acc = fmaf(gin[n], ti, acc);
            }
            (&aq.x)[jj] = acc;
        }
        yc[jb] = aq;
        xq0 = xq1;
        xq1 = xn;
    }
}

extern "C" void kernel_launch(void* const* d_in, const int* in_sizes, int n_in,
                              void* d_out, int out_size, void* d_ws, size_t ws_size,
                              hipStream_t stream) {
    const float* x       = (const float*)d_in[0];
    const float* alpha   = (const float*)d_in[1];
    const float* delta   = (const float*)d_in[2];
    const float* theta   = (const float*)d_in[3];
    const float* gamma_r = (const float*)d_in[4];
    const float* gamma_i = (const float*)d_in[5];
    const float* omega   = (const float*)d_in[6];
    float* out = (float*)d_out;
    float4* coef = (float4*)d_ws;            // D*NM float4 = 256 KiB

    coeff_kernel<<<(D * NM + 255) / 256, 256, 0, stream>>>(alpha, delta, theta,
                                                           gamma_r, gamma_i, coef);
    ema_kernel<<<(B * D) / 4, 256, 0, stream>>>(x, coef, omega, out);
}

// Round 5
// 44.415 us; speedup vs baseline: 4.1695x; 1.8290x over previous
//
#include <hip/hip_runtime.h>
#include <hip/hip_bf16.h>
#include <math.h>

// ComplexEMA via per-chunk Toeplitz MFMA + carry scan.
//   y[l] = sum_n Re(gp_n s_n[l]) + omega*x[l],  s_n[l] = q_n s_n[l-1] + x[l]
// Chunk size 32. Per d (one block): Y(32x512) = (T+wI)(32x32)*X(32x512)
//   + G(32x32)*Carry(32x512);  E = V*X gives chunk end-states; 64-lane
//   Kogge-Stone scan (weight q^32) turns E into carries. All matmuls are
//   f16 MFMA 16x16x32, f32 accum. Residual omega folded into T's diagonal.
// LDS: X/Carry in fragment-major tiles (1KB per 16-col tile), slot index
// XOR-swizzled (slot ^ ks) so MFMA B-reads are lane-linear ds_read_b128
// (conflict-free) AND staging writes spread banks. E/Y column-major with
// odd word strides (17 / 33). R2 lesson: no min-waves in launch_bounds.

#define Bc 8
#define Dc 1024
#define Lc 2048
#define NMc 16

typedef _Float16 f16x8 __attribute__((ext_vector_type(8)));
typedef float f32x4 __attribute__((ext_vector_type(4)));

// LDS byte offsets
#define X_OFF   0        // 32 tiles * 1024B = 32768
#define E_OFF   32768    // E_cm: uint word per mode, idx = col*17 + n (34816B)
#define C_OFF   32768    // carry frag tiles overlay E region (after B3)
#define TAB_OFF 67584    // qpr/qpi [16][33], gp, kap
#define FRG_OFF 72080    // T(2048) G(2048) V(2048)
#define SMEM_BYTES 78224

__global__ __launch_bounds__(512) void ema_mfma(const float* __restrict__ x,
                                                const float* __restrict__ alpha,
                                                const float* __restrict__ delta,
                                                const float* __restrict__ theta,
                                                const float* __restrict__ gamma_r,
                                                const float* __restrict__ gamma_i,
                                                const float* __restrict__ omega,
                                                float* __restrict__ out) {
    __shared__ __align__(16) char smem[SMEM_BYTES];
    const int tid = threadIdx.x;
    const int d = blockIdx.x;
    const int b = tid >> 6;      // wave = batch row
    const int l = tid & 63;

    float* qpr  = (float*)(smem + TAB_OFF);     // [16][33] powers of q
    float* qpi  = qpr + 16 * 33;
    float* gprs = qpi + 16 * 33;                // [16]
    float* gpis = gprs + 16;
    float* kap  = gpis + 16;                    // [33] kernel taps (+omega at 0)

    // ---- issue x loads early (dense 1KB per wave-instruction)
    const float4* xrow4 = (const float4*)(x + ((size_t)b * Dc + d) * Lc);
    float4 xv[8];
    #pragma unroll
    for (int i = 0; i < 8; ++i) xv[i] = xrow4[l + 64 * i];

    // ---- phase 0: per-mode coefficients + power table
    if (tid < NMc) {
        int n = tid, idx = d * NMc + n;
        float a  = 1.f / (1.f + __expf(-alpha[idx]));
        float dl = 1.f / (1.f + __expf(-delta[idx]));
        float th = (1.f / (1.f + __expf(-theta[d]))) * (6.283185307179586f / 16.f);
        float phi = (float)(n + 1) * th;
        float radius = fminf(1.f - a * dl, 1.f);
        float sn, cs; __sincosf(phi, &sn, &cs);
        float qr_ = radius * cs, qi_ = radius * sn;
        gprs[n] = gamma_r[idx] * 0.25f * a;
        gpis[n] = gamma_i[idx] * 0.25f * a;
        float pr = 1.f, pi = 0.f;
        qpr[n * 33] = 1.f; qpi[n * 33] = 0.f;
        for (int j = 1; j <= 32; ++j) {
            float t2 = pr * qr_ - pi * qi_;
            pi = pr * qi_ + pi * qr_;
            pr = t2;
            qpr[n * 33 + j] = pr; qpi[n * 33 + j] = pi;
        }
    }
    __syncthreads();                                        // B0
    if (tid < 33) {
        float s = 0.f;
        #pragma unroll
        for (int n = 0; n < 16; ++n)
            s += gprs[n] * qpr[n * 33 + tid] - gpis[n] * qpi[n * 33 + tid];
        if (tid == 0) s += omega[d];
        kap[tid] = s;
    }
    __syncthreads();                                        // B1

    // ---- fill T/G/V A-fragments (lane-linear layout), threads 0..383
    if (tid < 384) {
        int mat = tid >> 7;              // 0:T 1:G 2:V
        int sub = tid & 127;
        int rt = sub >> 6, ll = sub & 63;
        int row = rt * 16 + (ll & 15);
        int kb = 8 * (ll >> 4);
        union { _Float16 h[8]; f16x8 v; } fr;
        if (mat == 0) {
            #pragma unroll
            for (int j = 0; j < 8; ++j) {
                int dlt = row - (kb + j);
                fr.h[j] = (_Float16)((dlt >= 0) ? kap[dlt] : 0.f);
            }
        } else if (mat == 1) {
            #pragma unroll
            for (int j = 0; j < 8; ++j) {
                int k = kb + j, n = k >> 1;
                float qr_ = qpr[n * 33 + row + 1], qi_ = qpi[n * 33 + row + 1];
                float gr = gprs[n], gi = gpis[n];
                fr.h[j] = (_Float16)((k & 1) ? -(gr * qi_ + gi * qr_)
                                             : (gr * qr_ - gi * qi_));
            }
        } else {
            int n = row >> 1, im = row & 1;
            #pragma unroll
            for (int j = 0; j < 8; ++j) {
                int m = kb + j;
                fr.h[j] = (_Float16)(im ? qpi[n * 33 + 31 - m] : qpr[n * 33 + 31 - m]);
            }
        }
        *(f16x8*)(smem + FRG_OFF + mat * 2048 + (rt * 64 + ll) * 16) = fr.v;
    }

    // ---- stage X into fragment-major swizzled tiles (f16)
    #pragma unroll
    for (int i = 0; i < 8; ++i) {
        int f4 = l + 64 * i;
        int c = f4 >> 3;
        int ks = (f4 >> 1) & 3;
        int half = f4 & 1;
        int tc = b * 4 + (c >> 4);
        int slot = ks * 16 + (c & 15);
        int slotS = slot ^ ks;
        union { _Float16 h[4]; uint2 u; } pk;
        pk.h[0] = (_Float16)xv[i].x; pk.h[1] = (_Float16)xv[i].y;
        pk.h[2] = (_Float16)xv[i].z; pk.h[3] = (_Float16)xv[i].w;
        *(uint2*)(smem + X_OFF + tc * 1024 + slotS * 16 + half * 8) = pk.u;
    }
    __syncthreads();                                        // B2

    // ---- phase 2: E = V * X  (chunk end-states), write column-major f16
    const int fro = (l ^ (l >> 4)) * 16;     // lane-linear swizzled B-frag offset
    uint* Ew = (uint*)(smem + E_OFF);
    #pragma unroll
    for (int rt = 0; rt < 2; ++rt) {
        f16x8 va = *(const f16x8*)(smem + FRG_OFF + 2 * 2048 + (rt * 64 + l) * 16);
        #pragma unroll
        for (int tcl = 0; tcl < 4; ++tcl) {
            int tc = b * 4 + tcl;
            f16x8 xb = *(const f16x8*)(smem + X_OFF + tc * 1024 + fro);
            f32x4 acc = {0.f, 0.f, 0.f, 0.f};
            acc = __builtin_amdgcn_mfma_f32_16x16x32_f16(va, xb, acc, 0, 0, 0);
            int col = tc * 16 + (l & 15);
            int g = l >> 4;
            union { _Float16 h[2]; uint u; } p0, p1;
            p0.h[0] = (_Float16)acc[0]; p0.h[1] = (_Float16)acc[1];
            p1.h[0] = (_Float16)acc[2]; p1.h[1] = (_Float16)acc[3];
            Ew[col * 17 + 8 * rt + 2 * g]     = p0.u;
            Ew[col * 17 + 8 * rt + 2 * g + 1] = p1.u;
        }
    }

    // ---- phase 3: read own column, scan across 64 chunks, write carries
    float er[16], ei[16], wr_[16], wi_[16];
    {
        int col = b * 64 + l;
        #pragma unroll
        for (int n = 0; n < 16; ++n) {
            union { _Float16 h[2]; uint u; } pp;
            pp.u = Ew[col * 17 + n];
            er[n] = (float)pp.h[0];
            ei[n] = (float)pp.h[1];
            wr_[n] = qpr[n * 33 + 32];
            wi_[n] = qpi[n * 33 + 32];
        }
    }
    __syncthreads();                                        // B3 (E fully read)
    #pragma unroll
    for (int k = 1; k <= 32; k <<= 1) {
        #pragma unroll
        for (int n = 0; n < 16; ++n) {
            float or_ = __shfl_up(er[n], (unsigned)k, 64);
            float oi_ = __shfl_up(ei[n], (unsigned)k, 64);
            if (l >= k) {
                er[n] = fmaf(wr_[n], or_, fmaf(-wi_[n], oi_, er[n]));
                ei[n] = fmaf(wr_[n], oi_, fmaf(wi_[n], or_, ei[n]));
            }
        }
        if (k != 32) {
            #pragma unroll
            for (int n = 0; n < 16; ++n) {
                float t2 = fmaf(wr_[n], wr_[n], -(wi_[n] * wi_[n]));
                wi_[n] = 2.f * wr_[n] * wi_[n];
                wr_[n] = t2;
            }
        }
    }
    #pragma unroll
    for (int n = 0; n < 16; ++n) {           // exclusive: carry into chunk
        float cr = __shfl_up(er[n], 1u, 64);
        float ci = __shfl_up(ei[n], 1u, 64);
        er[n] = (l == 0) ? 0.f : cr;
        ei[n] = (l == 0) ? 0.f : ci;
    }
    {
        int tc = b * 4 + (l >> 4);
        #pragma unroll
        for (int ks = 0; ks < 4; ++ks) {
            union { _Float16 h[8]; f16x8 v; } hv;
            #pragma unroll
            for (int m = 0; m < 4; ++m) {
                hv.h[2 * m]     = (_Float16)er[4 * ks + m];
                hv.h[2 * m + 1] = (_Float16)ei[4 * ks + m];
            }
            int slot = ks * 16 + (l & 15);
            *(f16x8*)(smem + C_OFF + tc * 1024 + (slot ^ ks) * 16) = hv.v;
        }
    }

    // ---- phase 4: Y = (T+wI)*X + G*Carry
    f32x4 yacc[2][4];
    #pragma unroll
    for (int rt = 0; rt < 2; ++rt) {
        f16x8 ta = *(const f16x8*)(smem + FRG_OFF + (rt * 64 + l) * 16);
        f16x8 ga = *(const f16x8*)(smem + FRG_OFF + 2048 + (rt * 64 + l) * 16);
        #pragma unroll
        for (int tcl = 0; tcl < 4; ++tcl) {
            int tc = b * 4 + tcl;
            f16x8 xb = *(const f16x8*)(smem + X_OFF + tc * 1024 + fro);
            f16x8 cb = *(const f16x8*)(smem + C_OFF + tc * 1024 + fro);
            f32x4 a0 = {0.f, 0.f, 0.f, 0.f};
            a0 = __builtin_amdgcn_mfma_f32_16x16x32_f16(ta, xb, a0, 0, 0, 0);
            a0 = __builtin_amdgcn_mfma_f32_16x16x32_f16(ga, cb, a0, 0, 0, 0);
            yacc[rt][tcl] = a0;
        }
    }
    __syncthreads();                                        // B4 (X/C reads done)

    // ---- stage Y column-major (stride 33), then dense float4 stores
    float* Ycm = (float*)smem;
    #pragma unroll
    for (int rt = 0; rt < 2; ++rt) {
        #pragma unroll
        for (int tcl = 0; tcl < 4; ++tcl) {
            int col = (b * 4 + tcl) * 16 + (l & 15);
            int rb = rt * 16 + 4 * (l >> 4);
            #pragma unroll
            for (int r = 0; r < 4; ++r)
                Ycm[col * 33 + rb + r] = yacc[rt][tcl][r];
        }
    }
    __syncthreads();                                        // B5
    float4* orow4 = (float4*)(out + ((size_t)b * Dc + d) * Lc);
    #pragma unroll
    for (int i = 0; i < 8; ++i) {
        int f4 = l + 64 * i;
        int c = f4 >> 3;
        int t0 = (f4 & 7) * 4;
        int col = b * 64 + c;
        float4 o;
        o.x = Ycm[col * 33 + t0];
        o.y = Ycm[col * 33 + t0 + 1];
        o.z = Ycm[col * 33 + t0 + 2];
        o.w = Ycm[col * 33 + t0 + 3];
        orow4[f4] = o;
    }
}

extern "C" void kernel_launch(void* const* d_in, const int* in_sizes, int n_in,
                              void* d_out, int out_size, void* d_ws, size_t ws_size,
                              hipStream_t stream) {
    const float* x       = (const float*)d_in[0];
    const float* alpha   = (const float*)d_in[1];
    const float* delta   = (const float*)d_in[2];
    const float* theta   = (const float*)d_in[3];
    const float* gamma_r = (const float*)d_in[4];
    const float* gamma_i = (const float*)d_in[5];
    const float* omega   = (const float*)d_in[6];
    float* out = (float*)d_out;

    ema_mfma<<<Dc, 512, 0, stream>>>(x, alpha, delta, theta,
                                     gamma_r, gamma_i, omega, out);
}

// Round 6
// 41.000 us; speedup vs baseline: 4.5168x; 1.0833x over previous
//
#include <hip/hip_runtime.h>
#include <hip/hip_bf16.h>
#include <math.h>

// ComplexEMA via per-chunk Toeplitz MFMA + carry scan — split-kernel form.
//   Kernel 1 (prep): per-d coefficient tables -> T/G/V MFMA A-fragments +
//     q^32 scan weights in d_ws (6.4 MB). Runs the (cheap) serial power
//     table once per d, fully parallel over 1024 blocks.
//   Kernel 2 (main): ONE WAVE PER (b,d) ROW, 8192 blocks x 64 thr, no
//     cross-wave deps, LDS = 5.1 KB E/C transpose buffer only.
//     X B-fragments loaded straight from global (no LDS staging).
//     Y stored as full 64B sectors per instruction (no write amplification).
// Lessons kept: R2 no min-waves in launch_bounds (spill); R3 float4-aligned
// chunk-major LDS tiles conflict (use stride-20-word E/C buffer: uniform
// bank-quad coverage); R4 partial-line global stores amplify WRITE_SIZE
// (store sector-complete); R5 barriers+serial phase convoy (split kernels).

#define Bc 8
#define Dc 1024
#define Lc 2048
#define FRAG_STRIDE 6144                 // 3 mats * 2 rt * 64 lanes * 16B
#define SCANW_OFF (Dc * FRAG_STRIDE)     // then [d][16] float2 (128B per d)

typedef _Float16 f16x8 __attribute__((ext_vector_type(8)));
typedef float f32x4 __attribute__((ext_vector_type(4)));

__device__ inline uint pkh(float a, float b) {
    union { _Float16 h[2]; uint u; } p;
    p.h[0] = (_Float16)a; p.h[1] = (_Float16)b;
    return p.u;
}

__device__ inline f16x8 cvt8(float4 a, float4 b) {
    f16x8 h;
    h[0] = (_Float16)a.x; h[1] = (_Float16)a.y;
    h[2] = (_Float16)a.z; h[3] = (_Float16)a.w;
    h[4] = (_Float16)b.x; h[5] = (_Float16)b.y;
    h[6] = (_Float16)b.z; h[7] = (_Float16)b.w;
    return h;
}

__global__ __launch_bounds__(512) void prep_kernel(const float* __restrict__ alpha,
        const float* __restrict__ delta, const float* __restrict__ theta,
        const float* __restrict__ gamma_r, const float* __restrict__ gamma_i,
        const float* __restrict__ omega, char* __restrict__ ws) {
    __shared__ float qpr[16 * 33];
    __shared__ float qpi[16 * 33];
    __shared__ float gprs[16], gpis[16], kap[33];
    const int tid = threadIdx.x;
    const int d = blockIdx.x;

    if (tid < 16) {
        int n = tid, idx = d * 16 + n;
        float a  = 1.f / (1.f + __expf(-alpha[idx]));
        float dl = 1.f / (1.f + __expf(-delta[idx]));
        float th = (1.f / (1.f + __expf(-theta[d]))) * (6.283185307179586f / 16.f);
        float phi = (float)(n + 1) * th;
        float radius = fminf(1.f - a * dl, 1.f);
        float sn, cs; __sincosf(phi, &sn, &cs);
        float qr_ = radius * cs, qi_ = radius * sn;
        gprs[n] = gamma_r[idx] * 0.25f * a;
        gpis[n] = gamma_i[idx] * 0.25f * a;
        float pr = 1.f, pi = 0.f;
        qpr[n * 33] = 1.f; qpi[n * 33] = 0.f;
        for (int j = 1; j <= 32; ++j) {
            float t2 = pr * qr_ - pi * qi_;
            pi = pr * qi_ + pi * qr_;
            pr = t2;
            qpr[n * 33 + j] = pr; qpi[n * 33 + j] = pi;
        }
    }
    __syncthreads();
    if (tid < 33) {
        float s = 0.f;
        #pragma unroll
        for (int n = 0; n < 16; ++n)
            s += gprs[n] * qpr[n * 33 + tid] - gpis[n] * qpi[n * 33 + tid];
        if (tid == 0) s += omega[d];
        kap[tid] = s;
    }
    __syncthreads();
    if (tid < 384) {
        int mat = tid >> 7;              // 0:T 1:G 2:V
        int sub = tid & 127;
        int rt = sub >> 6, ll = sub & 63;
        int row = rt * 16 + (ll & 15);
        int kb = 8 * (ll >> 4);
        union { _Float16 h[8]; f16x8 v; } fr;
        if (mat == 0) {
            #pragma unroll
            for (int j = 0; j < 8; ++j) {
                int dlt = row - (kb + j);
                fr.h[j] = (_Float16)((dlt >= 0) ? kap[dlt] : 0.f);
            }
        } else if (mat == 1) {
            #pragma unroll
            for (int j = 0; j < 8; ++j) {
                int k = kb + j, n = k >> 1;
                float qr_ = qpr[n * 33 + row + 1], qi_ = qpi[n * 33 + row + 1];
                float gr = gprs[n], gi = gpis[n];
                fr.h[j] = (_Float16)((k & 1) ? -(gr * qi_ + gi * qr_)
                                             : (gr * qr_ - gi * qi_));
            }
        } else {
            int n = row >> 1, im = row & 1;
            #pragma unroll
            for (int j = 0; j < 8; ++j) {
                int mm = kb + j;
                fr.h[j] = (_Float16)(im ? qpi[n * 33 + 31 - mm] : qpr[n * 33 + 31 - mm]);
            }
        }
        *(f16x8*)(ws + (size_t)d * FRAG_STRIDE + mat * 2048 + (rt * 64 + ll) * 16) = fr.v;
    } else if (tid < 400) {
        int n = tid - 384;
        float2* sw = (float2*)(ws + SCANW_OFF);
        sw[d * 16 + n] = make_float2(qpr[n * 33 + 32], qpi[n * 33 + 32]);
    }
}

__global__ __launch_bounds__(64) void ema_main(const float* __restrict__ x,
        const char* __restrict__ ws, float* __restrict__ out) {
    __shared__ uint EC[64 * 20];         // 5120B: E then Carry, stride 20 words
    const int l = threadIdx.x;
    const int d = blockIdx.x & (Dc - 1);
    const int b = blockIdx.x >> 10;
    const int g = l >> 4;
    const int m = l & 15;
    const size_t rowoff = ((size_t)b * Dc + d) * Lc;
    const float4* xr4 = (const float4*)(x + rowoff);
    const f16x8* fr = (const f16x8*)(ws + (size_t)d * FRAG_STRIDE);

    // ---- X B-fragments direct from global (col=m, k=8g+j within tile)
    f16x8 xf0, xf1, xf2, xf3;
    {
        const int base = m * 8 + 2 * g;
        float4 a0 = xr4[base],       b0 = xr4[base + 1];
        float4 a1 = xr4[base + 128], b1 = xr4[base + 129];
        float4 a2 = xr4[base + 256], b2 = xr4[base + 257];
        float4 a3 = xr4[base + 384], b3 = xr4[base + 385];
        xf0 = cvt8(a0, b0); xf1 = cvt8(a1, b1);
        xf2 = cvt8(a2, b2); xf3 = cvt8(a3, b3);
    }

    // ---- E = V*X (chunk end-states), pack f16 pairs into EC
    {
        f16x8 va0 = fr[256 + l], va1 = fr[320 + l];
        #define EMFMA(VA, RT, TC, XF) { \
            f32x4 acc = {0.f, 0.f, 0.f, 0.f}; \
            acc = __builtin_amdgcn_mfma_f32_16x16x32_f16(VA, XF, acc, 0, 0, 0); \
            uint2 u; u.x = pkh(acc[0], acc[1]); u.y = pkh(acc[2], acc[3]); \
            *(uint2*)&EC[(TC * 16 + m) * 20 + 8 * RT + 2 * g] = u; }
        EMFMA(va0, 0, 0, xf0) EMFMA(va0, 0, 1, xf1)
        EMFMA(va0, 0, 2, xf2) EMFMA(va0, 0, 3, xf3)
        EMFMA(va1, 1, 0, xf0) EMFMA(va1, 1, 1, xf1)
        EMFMA(va1, 1, 2, xf2) EMFMA(va1, 1, 3, xf3)
        #undef EMFMA
    }
    __syncthreads();                     // single-wave: LDS ordering fence

    // ---- read own column (col = l), scan across 64 chunks
    float er[16], ei[16];
    #pragma unroll
    for (int k4 = 0; k4 < 4; ++k4) {
        uint4 q = *(const uint4*)&EC[l * 20 + 4 * k4];
        union { uint u; _Float16 h[2]; } p;
        p.u = q.x; er[4 * k4 + 0] = (float)p.h[0]; ei[4 * k4 + 0] = (float)p.h[1];
        p.u = q.y; er[4 * k4 + 1] = (float)p.h[0]; ei[4 * k4 + 1] = (float)p.h[1];
        p.u = q.z; er[4 * k4 + 2] = (float)p.h[0]; ei[4 * k4 + 2] = (float)p.h[1];
        p.u = q.w; er[4 * k4 + 3] = (float)p.h[0]; ei[4 * k4 + 3] = (float)p.h[1];
    }
    float wr_[16], wi_[16];
    {
        const float2* sw = (const float2*)(ws + SCANW_OFF + (size_t)d * 128);
        #pragma unroll
        for (int n = 0; n < 16; ++n) { float2 t = sw[n]; wr_[n] = t.x; wi_[n] = t.y; }
    }
    #pragma unroll
    for (int k = 1; k <= 32; k <<= 1) {
        #pragma unroll
        for (int n = 0; n < 16; ++n) {
            float or_ = __shfl_up(er[n], (unsigned)k, 64);
            float oi_ = __shfl_up(ei[n], (unsigned)k, 64);
            if (l >= k) {
                er[n] = fmaf(wr_[n], or_, fmaf(-wi_[n], oi_, er[n]));
                ei[n] = fmaf(wr_[n], oi_, fmaf(wi_[n], or_, ei[n]));
            }
        }
        if (k != 32) {
            #pragma unroll
            for (int n = 0; n < 16; ++n) {
                float t2 = fmaf(wr_[n], wr_[n], -(wi_[n] * wi_[n]));
                wi_[n] = 2.f * wr_[n] * wi_[n];
                wr_[n] = t2;
            }
        }
    }
    #pragma unroll
    for (int n = 0; n < 16; ++n) {       // exclusive: carry entering chunk l
        float cr = __shfl_up(er[n], 1u, 64);
        float ci = __shfl_up(ei[n], 1u, 64);
        er[n] = (l == 0) ? 0.f : cr;
        ei[n] = (l == 0) ? 0.f : ci;
    }

    // ---- write carries back (same layout), then consume as B-fragments
    #pragma unroll
    for (int k4 = 0; k4 < 4; ++k4) {
        uint4 cw;
        cw.x = pkh(er[4 * k4 + 0], ei[4 * k4 + 0]);
        cw.y = pkh(er[4 * k4 + 1], ei[4 * k4 + 1]);
        cw.z = pkh(er[4 * k4 + 2], ei[4 * k4 + 2]);
        cw.w = pkh(er[4 * k4 + 3], ei[4 * k4 + 3]);
        *(uint4*)&EC[l * 20 + 4 * k4] = cw;
    }
    __syncthreads();                     // single-wave: LDS ordering fence

    // ---- Y = (T+wI)*X + G*Carry; store full 64B sectors per instruction
    {
        f16x8 ta0 = fr[l], ta1 = fr[64 + l];
        f16x8 ga0 = fr[128 + l], ga1 = fr[192 + l];
        float4* or4 = (float4*)(out + rowoff);
        #define YTILE(TC, XF) { \
            f16x8 cb = *(const f16x8*)&EC[(TC * 16 + m) * 20 + 4 * g]; \
            f32x4 y0 = {0.f, 0.f, 0.f, 0.f}, y1 = {0.f, 0.f, 0.f, 0.f}; \
            y0 = __builtin_amdgcn_mfma_f32_16x16x32_f16(ta0, XF, y0, 0, 0, 0); \
            y0 = __builtin_amdgcn_mfma_f32_16x16x32_f16(ga0, cb, y0, 0, 0, 0); \
            y1 = __builtin_amdgcn_mfma_f32_16x16x32_f16(ta1, XF, y1, 0, 0, 0); \
            y1 = __builtin_amdgcn_mfma_f32_16x16x32_f16(ga1, cb, y1, 0, 0, 0); \
            float4 o0, o1; \
            o0.x = y0[0]; o0.y = y0[1]; o0.z = y0[2]; o0.w = y0[3]; \
            o1.x = y1[0]; o1.y = y1[1]; o1.z = y1[2]; o1.w = y1[3]; \
            or4[(TC * 16 + m) * 8 + g]     = o0; \
            or4[(TC * 16 + m) * 8 + 4 + g] = o1; }
        YTILE(0, xf0) YTILE(1, xf1) YTILE(2, xf2) YTILE(3, xf3)
        #undef YTILE
    }
}

extern "C" void kernel_launch(void* const* d_in, const int* in_sizes, int n_in,
                              void* d_out, int out_size, void* d_ws, size_t ws_size,
                              hipStream_t stream) {
    const float* x       = (const float*)d_in[0];
    const float* alpha   = (const float*)d_in[1];
    const float* delta   = (const float*)d_in[2];
    const float* theta   = (const float*)d_in[3];
    const float* gamma_r = (const float*)d_in[4];
    const float* gamma_i = (const float*)d_in[5];
    const float* omega   = (const float*)d_in[6];
    float* out = (float*)d_out;
    // ws usage: 1024*6144 + 1024*128 = 6,422,528 bytes
    char* ws = (char*)d_ws;

    prep_kernel<<<Dc, 512, 0, stream>>>(alpha, delta, theta,
                                        gamma_r, gamma_i, omega, ws);
    ema_main<<<Bc * Dc, 64, 0, stream>>>(x, ws, out);
}